// Round 12
// baseline (78.618 us; speedup 1.0000x reference)
//
#include <hip/hip_runtime.h>

typedef __attribute__((ext_vector_type(8))) short bf16x8;
typedef __attribute__((ext_vector_type(4))) float f32x4;

static constexpr int N_NODES = 8192;   // B*L
static constexpr int FEAT    = 128;
static constexpr int NB      = 16;     // nodes per fused block
static constexpr int NBLK    = N_NODES / NB;   // 512 blocks
static constexpr int XS      = 136;    // LDS X row stride (bf16): 272B, 16B-aligned
static constexpr int FEAT_BLOCKS = 6250;  // 100000*128/8 floats / 256 threads

__device__ __forceinline__ unsigned short f2bf(float f) {
    unsigned u = __builtin_bit_cast(unsigned, f);
    u += 0x7FFFu + ((u >> 16) & 1u);   // round-to-nearest-even
    return (unsigned short)(u >> 16);
}
__device__ __forceinline__ float bf2f(unsigned short h) {
    return __builtin_bit_cast(float, ((unsigned)h) << 16);
}
__device__ __forceinline__ void acc8(float* a, const uint4 v) {
    a[0] += bf2f((unsigned short)(v.x & 0xffffu));
    a[1] += bf2f((unsigned short)(v.x >> 16));
    a[2] += bf2f((unsigned short)(v.y & 0xffffu));
    a[3] += bf2f((unsigned short)(v.y >> 16));
    a[4] += bf2f((unsigned short)(v.z & 0xffffu));
    a[5] += bf2f((unsigned short)(v.z >> 16));
    a[6] += bf2f((unsigned short)(v.w & 0xffffu));
    a[7] += bf2f((unsigned short)(v.w >> 16));
}
__device__ __forceinline__ uint4 pack8(const float* a, float sc) {
    uint4 o;
    o.x = (unsigned)f2bf(a[0] * sc) | ((unsigned)f2bf(a[1] * sc) << 16);
    o.y = (unsigned)f2bf(a[2] * sc) | ((unsigned)f2bf(a[3] * sc) << 16);
    o.z = (unsigned)f2bf(a[4] * sc) | ((unsigned)f2bf(a[5] * sc) << 16);
    o.w = (unsigned)f2bf(a[6] * sc) | ((unsigned)f2bf(a[7] * sc) << 16);
    return o;
}

// ---------------- Kernel 0: pack features + W fp32 -> bf16 ----------------
__global__ void __launch_bounds__(256) pack_all(
    const float* __restrict__ feat, const float* __restrict__ lw,
    unsigned short* __restrict__ T, unsigned short* __restrict__ Wp)
{
    const int b = blockIdx.x;
    if (b < FEAT_BLOCKS) {
        const size_t i = (size_t)b * 256 + threadIdx.x;
        const f32x4* src = (const f32x4*)feat;
        const f32x4 v0 = __builtin_nontemporal_load(src + i * 2);
        const f32x4 v1 = __builtin_nontemporal_load(src + i * 2 + 1);
        ushort4 o0, o1;
        o0.x = f2bf(v0[0]); o0.y = f2bf(v0[1]); o0.z = f2bf(v0[2]); o0.w = f2bf(v0[3]);
        o1.x = f2bf(v1[0]); o1.y = f2bf(v1[1]); o1.z = f2bf(v1[2]); o1.w = f2bf(v1[3]);
        ((ushort4*)T)[i * 2]     = o0;
        ((ushort4*)T)[i * 2 + 1] = o1;
    } else {
        const int i = (b - FEAT_BLOCKS) * 256 + threadIdx.x;
        const float4 v = ((const float4*)lw)[i];
        ushort4 o;
        o.x = f2bf(v.x); o.y = f2bf(v.y); o.z = f2bf(v.z); o.w = f2bf(v.w);
        ((ushort4*)Wp)[i] = o;
    }
}

// ---------------- Fused: gather -> LDS X -> MFMA GEMM + ReLU (512 threads) ----
// 8 waves. Gather: node i <- groups 2i (1hop+self+2hop[10..59]) and 2i+1
// (2hop[60..109]); odd half's partial combined via LDS red[].
// GEMM: M=48 x N=1024 (8 waves x 2 chunks of 64) x K=128, scattered epilogue
// (round-11-verified patterns throughout).
__global__ void __launch_bounds__(512) fused_enc(
    const unsigned short* __restrict__ T,
    const int*   __restrict__ nodes,
    const int*   __restrict__ n1,
    const int*   __restrict__ n2,
    const unsigned short* __restrict__ Wp,
    float* __restrict__ out)
{
    __shared__ int nfs[NB];
    __shared__ int sm_m[NB][10];
    __shared__ int idx[NB][112];              // [0..9]=1hop, [10..109]=2hop, [110]=self
    __shared__ unsigned short X[3 * NB][XS];  // 48 x 136 bf16
    __shared__ float red[NB][FEAT];           // odd-half aB partials (fp32)

    const int blk = blockIdx.x;
    const int tid = threadIdx.x;

    // ---- phase 1: indices (disjoint mapping for 512 threads) ----
    if (tid < NB) nfs[tid] = nodes[blk * NB + tid];
    __syncthreads();
    if (tid < 160) {                           // 1-hop
        const int i = tid / 10, s = tid - (tid / 10) * 10;
        idx[i][s] = n1[nfs[i] * 10 + s];
    } else if (tid < 320) {                    // 2-hop seeds
        const int t = tid - 160;
        const int i = t / 10, s = t - (t / 10) * 10;
        sm_m[i][s] = n2[nfs[i] * 10 + s];
    } else if (tid < 320 + NB) {
        idx[tid - 320][110] = nfs[tid - 320];
    }
    __syncthreads();
    for (int t = tid; t < NB * 100; t += 512) { // 1600 two-hop rows
        const int i = t / 100, rr = t - (t / 100) * 100;
        idx[i][10 + rr] = n1[sm_m[i][rr / 10] * 10 + (rr - (rr / 10) * 10)];
    }
    __syncthreads();

    // ---- phase 2: gather, two 16-lane groups per node ----
    {
        const int grp  = tid >> 4;     // 0..31
        const int node = grp >> 1;     // 0..15
        const int half = grp & 1;
        const int l    = tid & 15;     // dims l*8 .. l*8+7
        const unsigned short* Tl = T + l * 8;

        float aA[8] = {0,0,0,0,0,0,0,0};
        float aB[8] = {0,0,0,0,0,0,0,0};
        uint4 v[10];

        if (!half) {
            // 1-hop rows 0..9
#pragma unroll
            for (int s = 0; s < 10; ++s)
                v[s] = *(const uint4*)(Tl + (size_t)idx[node][s] * FEAT);
#pragma unroll
            for (int s = 0; s < 10; ++s) acc8(aA, v[s]);
            // 2-hop rows 10..59 (chunks 1..5)
#pragma unroll
            for (int c = 1; c <= 5; ++c) {
#pragma unroll
                for (int s = 0; s < 10; ++s)
                    v[s] = *(const uint4*)(Tl + (size_t)idx[node][c * 10 + s] * FEAT);
#pragma unroll
                for (int s = 0; s < 10; ++s) acc8(aB, v[s]);
            }
        } else {
            // 2-hop rows 60..109 (chunks 6..10)
#pragma unroll
            for (int c = 6; c <= 10; ++c) {
#pragma unroll
                for (int s = 0; s < 10; ++s)
                    v[s] = *(const uint4*)(Tl + (size_t)idx[node][c * 10 + s] * FEAT);
#pragma unroll
                for (int s = 0; s < 10; ++s) acc8(aB, v[s]);
            }
            // stage partial for even half
#pragma unroll
            for (int h = 0; h < 2; ++h)
                *(f32x4*)&red[node][l * 8 + h * 4] = *(const f32x4*)&aB[h * 4];
        }
        __syncthreads();
        if (!half) {
            const uint4 sv = *(const uint4*)(Tl + (size_t)idx[node][110] * FEAT);
#pragma unroll
            for (int h = 0; h < 8; ++h) aB[h] += red[node][l * 8 + h];
            *(uint4*)&X[node * 3 + 2][l * 8] = sv;
            *(uint4*)&X[node * 3 + 0][l * 8] = pack8(aA, 0.1f);
            *(uint4*)&X[node * 3 + 1][l * 8] = pack8(aB, 0.01f);
        }
    }
    __syncthreads();

    // ---- phase 3: GEMM M=48 x N=1024 x K=128 + ReLU, scattered epilogue ----
    const int wave = tid >> 6;     // 0..7
    const int lane = tid & 63;
    const int r = lane & 15;       // A row / B col within 16-tile
    const int q = lane >> 4;       // k-slot (8 contiguous K elems)

#pragma unroll
    for (int ch = 0; ch < 2; ++ch) {
        const int yBase = wave * 128 + ch * 64;
        f32x4 acc[3][4];
#pragma unroll
        for (int mt = 0; mt < 3; ++mt)
#pragma unroll
            for (int nj = 0; nj < 4; ++nj) acc[mt][nj] = (f32x4){0.f, 0.f, 0.f, 0.f};

#pragma unroll
        for (int k0 = 0; k0 < 4; ++k0) {
            bf16x8 a[3], b[4];
#pragma unroll
            for (int mt = 0; mt < 3; ++mt)
                a[mt] = *(const bf16x8*)&X[mt * 16 + r][k0 * 32 + q * 8];
#pragma unroll
            for (int nj = 0; nj < 4; ++nj)
                b[nj] = *(const bf16x8*)(Wp + (size_t)(yBase + nj * 16 + r) * FEAT
                                            + q * 8 + k0 * 32);
#pragma unroll
            for (int mt = 0; mt < 3; ++mt)
#pragma unroll
                for (int nj = 0; nj < 4; ++nj)
                    acc[mt][nj] = __builtin_amdgcn_mfma_f32_16x16x32_bf16(
                        a[mt], b[nj], acc[mt][nj], 0, 0, 0);
        }

        // round-11-verified scattered epilogue: C/D row = q*4+i, col = r.
#pragma unroll
        for (int mt = 0; mt < 3; ++mt) {
#pragma unroll
            for (int i = 0; i < 4; ++i) {
                const int xl = mt * 16 + q * 4 + i;   // 0..47
                const int nl = xl / 3;
                const int j  = xl - nl * 3;
                float* orow = out + (size_t)(blk * NB + nl) * 3072 + j * 128;
#pragma unroll
                for (int nj = 0; nj < 4; ++nj) {
                    const int y = yBase + nj * 16 + r;
                    const int c = y >> 7;
                    const int k = y & 127;
                    orow[c * 384 + k] = fmaxf(acc[mt][nj][i], 0.f);
                }
            }
        }
    }
}

extern "C" void kernel_launch(void* const* d_in, const int* in_sizes, int n_in,
                              void* d_out, int out_size, void* d_ws, size_t ws_size,
                              hipStream_t stream) {
    const float* features = (const float*)d_in[0];   // [100000,128] f32
    const float* lw       = (const float*)d_in[1];   // [8,128,128]  f32
    const int*   nodes    = (const int*)d_in[2];     // [1024,8]     i32
    const int*   n1       = (const int*)d_in[3];     // [100000,10]  i32
    const int*   n2       = (const int*)d_in[4];     // [100000,10]  i32
    float*       out      = (float*)d_out;           // [1024,8,8,384] f32

    unsigned short* Wp = (unsigned short*)d_ws;              // 1024*128 bf16 = 256 KB
    unsigned short* T  = Wp + (size_t)1024 * FEAT;           // 100000*128 bf16 = 25.6 MB

    pack_all<<<FEAT_BLOCKS + 128, 256, 0, stream>>>(features, lw, T, Wp);
    fused_enc<<<NBLK, 512, 0, stream>>>(T, nodes, n1, n2, Wp, out);
}

// Round 13
// 61.373 us; speedup vs baseline: 1.2810x; 1.2810x over previous
//
#include <hip/hip_runtime.h>

typedef __attribute__((ext_vector_type(8))) short bf16x8;
typedef __attribute__((ext_vector_type(4))) float f32x4;

static constexpr int N_NODES = 8192;   // B*L
static constexpr int FEAT    = 128;
static constexpr int NB      = 16;     // nodes per fused block
static constexpr int NBLK    = N_NODES / NB;   // 512 blocks
static constexpr int XS      = 136;    // LDS X row stride (bf16): 272B, 16B-aligned
static constexpr int FEAT_BLOCKS = 6250;  // 100000*128/8 floats / 256 threads

__device__ __forceinline__ unsigned short f2bf(float f) {
    unsigned u = __builtin_bit_cast(unsigned, f);
    u += 0x7FFFu + ((u >> 16) & 1u);   // round-to-nearest-even
    return (unsigned short)(u >> 16);
}
__device__ __forceinline__ float bf2f(unsigned short h) {
    return __builtin_bit_cast(float, ((unsigned)h) << 16);
}
// f32 -> e4m3fn, RNE, satfinite. Alignment trick: af*2^-120 puts the e4m3
// em-field at f32 bits [26:20] (exact, incl. subnormals); round at bit 20.
__device__ __forceinline__ unsigned f2fp8(float f) {
    unsigned u = __builtin_bit_cast(unsigned, f);
    unsigned s = (u >> 24) & 0x80u;
    float af = __builtin_bit_cast(float, u & 0x7fffffffu);
    if (!(af < 448.f)) af = 448.f;
    unsigned q = __builtin_bit_cast(unsigned, af * 0x1p-120f);
    unsigned b = (q + 0x7FFFFu + ((q >> 20) & 1u)) >> 20;
    return s | b;
}
__device__ __forceinline__ void acc8(float* a, const uint4 v) {
    a[0] += bf2f((unsigned short)(v.x & 0xffffu));
    a[1] += bf2f((unsigned short)(v.x >> 16));
    a[2] += bf2f((unsigned short)(v.y & 0xffffu));
    a[3] += bf2f((unsigned short)(v.y >> 16));
    a[4] += bf2f((unsigned short)(v.z & 0xffffu));
    a[5] += bf2f((unsigned short)(v.z >> 16));
    a[6] += bf2f((unsigned short)(v.w & 0xffffu));
    a[7] += bf2f((unsigned short)(v.w >> 16));
}
// e4m3fn decode: byte to top, ashr 4 (em -> [26:20], sign stays at 31),
// mask sext junk, then value = bits * 2^120 folded into the fma.
__device__ __forceinline__ void acc8f8(float* a, const uint2 v) {
#pragma unroll
    for (int i = 0; i < 4; ++i) {
        unsigned t = v.x << (24 - 8 * i);
        unsigned w = (unsigned)((int)t >> 4) & 0x87F00000u;
        a[i] = fmaf(__builtin_bit_cast(float, w), 0x1p120f, a[i]);
    }
#pragma unroll
    for (int i = 0; i < 4; ++i) {
        unsigned t = v.y << (24 - 8 * i);
        unsigned w = (unsigned)((int)t >> 4) & 0x87F00000u;
        a[4 + i] = fmaf(__builtin_bit_cast(float, w), 0x1p120f, a[4 + i]);
    }
}
__device__ __forceinline__ uint4 pack8(const float* a, float sc) {
    uint4 o;
    o.x = (unsigned)f2bf(a[0] * sc) | ((unsigned)f2bf(a[1] * sc) << 16);
    o.y = (unsigned)f2bf(a[2] * sc) | ((unsigned)f2bf(a[3] * sc) << 16);
    o.z = (unsigned)f2bf(a[4] * sc) | ((unsigned)f2bf(a[5] * sc) << 16);
    o.w = (unsigned)f2bf(a[6] * sc) | ((unsigned)f2bf(a[7] * sc) << 16);
    return o;
}

// ---------------- Kernel 0: pack features (bf16 + fp8) + W fp32 -> bf16 ----------------
__global__ void __launch_bounds__(256) pack_all(
    const float* __restrict__ feat, const float* __restrict__ lw,
    unsigned short* __restrict__ T, unsigned char* __restrict__ T8,
    unsigned short* __restrict__ Wp)
{
    const int b = blockIdx.x;
    if (b < FEAT_BLOCKS) {
        const size_t i = (size_t)b * 256 + threadIdx.x;
        const f32x4* src = (const f32x4*)feat;
        const f32x4 v0 = __builtin_nontemporal_load(src + i * 2);
        const f32x4 v1 = __builtin_nontemporal_load(src + i * 2 + 1);
        ushort4 o0, o1;
        o0.x = f2bf(v0[0]); o0.y = f2bf(v0[1]); o0.z = f2bf(v0[2]); o0.w = f2bf(v0[3]);
        o1.x = f2bf(v1[0]); o1.y = f2bf(v1[1]); o1.z = f2bf(v1[2]); o1.w = f2bf(v1[3]);
        ((ushort4*)T)[i * 2]     = o0;
        ((ushort4*)T)[i * 2 + 1] = o1;
        uint2 p;
        p.x = f2fp8(v0[0]) | (f2fp8(v0[1]) << 8) | (f2fp8(v0[2]) << 16) | (f2fp8(v0[3]) << 24);
        p.y = f2fp8(v1[0]) | (f2fp8(v1[1]) << 8) | (f2fp8(v1[2]) << 16) | (f2fp8(v1[3]) << 24);
        ((uint2*)T8)[i] = p;
    } else {
        const int i = (b - FEAT_BLOCKS) * 256 + threadIdx.x;
        const float4 v = ((const float4*)lw)[i];
        ushort4 o;
        o.x = f2bf(v.x); o.y = f2bf(v.y); o.z = f2bf(v.z); o.w = f2bf(v.w);
        ((ushort4*)Wp)[i] = o;
    }
}

// ---------------- Fused: gather -> LDS X -> MFMA GEMM + ReLU ----------------
// r11-verified structure; 2-hop rows read from fp8 table T8 (128B rows).
__global__ void __launch_bounds__(256) fused_enc(
    const unsigned short* __restrict__ T,
    const unsigned char*  __restrict__ T8,
    const int*   __restrict__ nodes,
    const int*   __restrict__ n1,
    const int*   __restrict__ n2,
    const unsigned short* __restrict__ Wp,
    float* __restrict__ out)
{
    __shared__ int nfs[NB];
    __shared__ int sm_m[NB][10];
    __shared__ int idx[NB][112];              // [0..9]=1hop, [10..109]=2hop, [110]=self
    __shared__ unsigned short X[3 * NB][XS];  // 48 x 136 bf16

    const int blk = blockIdx.x;
    const int tid = threadIdx.x;

    // ---- phase 1: indices (r11-verified) ----
    if (tid < NB) nfs[tid] = nodes[blk * NB + tid];
    __syncthreads();
    if (tid < NB * 10) {                       // 160 threads: 1-hop
        const int i = tid / 10, s = tid - (tid / 10) * 10;
        idx[i][s] = n1[nfs[i] * 10 + s];
    }
    if (tid >= 96) {                           // 160 threads: 2-hop seeds
        const int t = tid - 96;
        const int i = t / 10, s = t - (t / 10) * 10;
        sm_m[i][s] = n2[nfs[i] * 10 + s];
    }
    if (tid < NB) idx[tid][110] = nfs[tid];
    __syncthreads();
    for (int t = tid; t < NB * 100; t += 256) { // 1600 two-hop rows
        const int i = t / 100, rr = t - (t / 100) * 100;
        idx[i][10 + rr] = n1[sm_m[i][rr / 10] * 10 + (rr - (rr / 10) * 10)];
    }
    __syncthreads();

    // ---- phase 2: gather (1-hop/self bf16, 2-hop fp8), write LDS X ----
    {
        const int g = tid >> 4;    // node_local 0..15
        const int l = tid & 15;    // dims l*8 .. l*8+7
        const unsigned short* Tl  = T  + l * 8;
        const unsigned char*  Tl8 = T8 + l * 8;

        float aA[8] = {0,0,0,0,0,0,0,0};
        float aB[8] = {0,0,0,0,0,0,0,0};

        {   // chunk 0: rows 0..9 -> 1-hop (bf16)
            uint4 v[10];
#pragma unroll
            for (int s = 0; s < 10; ++s)
                v[s] = *(const uint4*)(Tl + (size_t)idx[g][s] * FEAT);
#pragma unroll
            for (int s = 0; s < 10; ++s) acc8(aA, v[s]);
        }
        // chunks 1..10: rows 10..109 -> 2-hop (fp8, 8B/lane)
#pragma unroll
        for (int c = 1; c <= 10; ++c) {
            uint2 v8[10];
#pragma unroll
            for (int s = 0; s < 10; ++s)
                v8[s] = *(const uint2*)(Tl8 + (size_t)idx[g][c * 10 + s] * FEAT);
#pragma unroll
            for (int s = 0; s < 10; ++s) acc8f8(aB, v8[s]);
        }
        const uint4 sv = *(const uint4*)(Tl + (size_t)idx[g][110] * FEAT);
        *(uint4*)&X[g * 3 + 2][l * 8] = sv;
        *(uint4*)&X[g * 3 + 0][l * 8] = pack8(aA, 0.1f);
        *(uint4*)&X[g * 3 + 1][l * 8] = pack8(aB, 0.01f);
    }
    __syncthreads();

    // ---- phase 3: GEMM M=48 x N=1024 x K=128 + ReLU, scattered epilogue ----
    const int wave = tid >> 6;
    const int lane = tid & 63;
    const int r = lane & 15;   // A row / B col within 16-tile
    const int q = lane >> 4;   // k-slot (8 contiguous K elems)

#pragma unroll
    for (int ch = 0; ch < 4; ++ch) {
        const int yBase = wave * 256 + ch * 64;
        f32x4 acc[3][4];
#pragma unroll
        for (int mt = 0; mt < 3; ++mt)
#pragma unroll
            for (int nj = 0; nj < 4; ++nj) acc[mt][nj] = (f32x4){0.f, 0.f, 0.f, 0.f};

#pragma unroll
        for (int k0 = 0; k0 < 4; ++k0) {
            bf16x8 a[3], b[4];
#pragma unroll
            for (int mt = 0; mt < 3; ++mt)
                a[mt] = *(const bf16x8*)&X[mt * 16 + r][k0 * 32 + q * 8];
#pragma unroll
            for (int nj = 0; nj < 4; ++nj)
                b[nj] = *(const bf16x8*)(Wp + (size_t)(yBase + nj * 16 + r) * FEAT
                                            + q * 8 + k0 * 32);
#pragma unroll
            for (int mt = 0; mt < 3; ++mt)
#pragma unroll
                for (int nj = 0; nj < 4; ++nj)
                    acc[mt][nj] = __builtin_amdgcn_mfma_f32_16x16x32_bf16(
                        a[mt], b[nj], acc[mt][nj], 0, 0, 0);
        }

        // r11-verified scattered epilogue: C/D row = q*4+i, col = r.
#pragma unroll
        for (int mt = 0; mt < 3; ++mt) {
#pragma unroll
            for (int i = 0; i < 4; ++i) {
                const int xl = mt * 16 + q * 4 + i;   // 0..47
                const int nl = xl / 3;
                const int j  = xl - nl * 3;
                float* orow = out + (size_t)(blk * NB + nl) * 3072 + j * 128;
#pragma unroll
                for (int nj = 0; nj < 4; ++nj) {
                    const int y = yBase + nj * 16 + r;
                    const int c = y >> 7;
                    const int k = y & 127;
                    orow[c * 384 + k] = fmaxf(acc[mt][nj][i], 0.f);
                }
            }
        }
    }
}

extern "C" void kernel_launch(void* const* d_in, const int* in_sizes, int n_in,
                              void* d_out, int out_size, void* d_ws, size_t ws_size,
                              hipStream_t stream) {
    const float* features = (const float*)d_in[0];   // [100000,128] f32
    const float* lw       = (const float*)d_in[1];   // [8,128,128]  f32
    const int*   nodes    = (const int*)d_in[2];     // [1024,8]     i32
    const int*   n1       = (const int*)d_in[3];     // [100000,10]  i32
    const int*   n2       = (const int*)d_in[4];     // [100000,10]  i32
    float*       out      = (float*)d_out;           // [1024,8,8,384] f32

    unsigned short* Wp = (unsigned short*)d_ws;              // 1024*128 bf16 = 256 KB
    unsigned short* T  = Wp + (size_t)1024 * FEAT;           // 100000*128 bf16 = 25.6 MB
    unsigned char*  T8 = (unsigned char*)(T + (size_t)100000 * FEAT);  // 12.8 MB

    pack_all<<<FEAT_BLOCKS + 128, 256, 0, stream>>>(features, lw, T, T8, Wp);
    fused_enc<<<NBLK, 256, 0, stream>>>(T, T8, nodes, n1, n2, Wp, out);
}